// Round 5
// baseline (319.971 us; speedup 1.0000x reference)
//
#include <hip/hip_runtime.h>

// Problem constants
#define NBANDS 64
#define LATENT 256
#define HIDDEN 512
#define GQ 8
#define KQ 1024
#define GD 32
#define NROWS 16000   // B*T = 16*1000

// d_out float offsets
#define OUT_BH   0
#define OUT_ZE   1024000
#define OUT_ZQ   5120000
#define OUT_IDX  9216000
#define OUT_LOSS 9344000

// ws float offsets.  H region [0,8192000) is live ONLY between enc1 and enc2;
// bf16 buffers overlay it and MUST be written after enc2.
#define WS_H     0
#define WS_H2BF_F  0
#define WS_ZQB_F   4096000
#define WS_W1B_F   6144000
#define WS_W2B_F   6209536
// 3-way bf16 split of codebooks (written by prep_wT, read by vq_mfma).
// 262144 ushort = 131072 floats each; all inside dead-H overlay region.
#define WS_CBH_F   6240000
#define WS_CBM_F   6400000
#define WS_CBL_F   6560000
#define WS_CN    8192000
#define WS_LOSS  8200192

typedef __attribute__((ext_vector_type(8))) short bf16x8;
typedef __attribute__((ext_vector_type(4))) float f32x4;

__device__ __forceinline__ unsigned short f2bf(float f) {
  unsigned u = __builtin_bit_cast(unsigned, f);
  unsigned r = u + 0x7FFFu + ((u >> 16) & 1u);   // RNE; inputs finite
  return (unsigned short)(r >> 16);
}

__device__ __forceinline__ float bf2f(unsigned short h) {
  return __builtin_bit_cast(float, ((unsigned)h) << 16);
}

// 3-way bf16 split: x ~= h + m + l with residual ~2^-24 |x|.
__device__ __forceinline__ void split3(float x, unsigned short& h,
                                       unsigned short& m, unsigned short& l) {
  h = f2bf(x);
  const float r1 = x - bf2f(h);
  m = f2bf(r1);
  const float r2 = r1 - bf2f(m);
  l = f2bf(r2);
}

// ---------------------------------------------------------------------------
// fp32 GEMM, 128xBN tile, TMxTN microtile, templated BK, 256 threads.
// Ascending-k accumulation regardless of BK -> bit-identical results.
// ---------------------------------------------------------------------------
template<int BN, int TM, int TN, int BK, bool RELU>
__global__ __launch_bounds__(256) void gemm_f32(
    const float* __restrict__ A, const float* __restrict__ B,
    const float* __restrict__ bias, float* __restrict__ C,
    int M, int N, int K) {
  constexpr int BM = 128;
  constexpr int NTX = BN / TN;
  constexpr int AF4 = BK / 8;
  constexpr int QPR = BN / 4;
  constexpr int BF4 = BK * BN / 1024;

  __shared__ float As[BK][BM + 8];
  __shared__ float Bs[BK][BN + 4];

  const int tid = threadIdx.x;
  const int tx = tid % NTX;
  const int ty = tid / NTX;
  const int row0 = blockIdx.y * BM;
  const int col0 = blockIdx.x * BN;

  const int arow = tid >> 1;
  const int akq  = (tid & 1) * (BK / 2);

  float acc[TM][TN] = {};

  for (int k0 = 0; k0 < K; k0 += BK) {
    float4 av[AF4], bv[BF4];
#pragma unroll
    for (int q = 0; q < AF4; ++q)
      av[q] = *reinterpret_cast<const float4*>(
          &A[(size_t)(row0 + arow) * K + k0 + akq + q * 4]);
#pragma unroll
    for (int t = 0; t < BF4; ++t) {
      const int qq = tid * BF4 + t;
      const int bk = qq / QPR, bn4 = qq % QPR;
      bv[t] = *reinterpret_cast<const float4*>(
          &B[(size_t)(k0 + bk) * N + col0 + bn4 * 4]);
    }
    __syncthreads();
#pragma unroll
    for (int q = 0; q < AF4; ++q) {
      As[akq + q * 4 + 0][arow] = av[q].x;
      As[akq + q * 4 + 1][arow] = av[q].y;
      As[akq + q * 4 + 2][arow] = av[q].z;
      As[akq + q * 4 + 3][arow] = av[q].w;
    }
#pragma unroll
    for (int t = 0; t < BF4; ++t) {
      const int qq = tid * BF4 + t;
      const int bk = qq / QPR, bn4 = qq % QPR;
      *reinterpret_cast<float4*>(&Bs[bk][bn4 * 4]) = bv[t];
    }
    __syncthreads();

#pragma unroll
    for (int kk = 0; kk < BK; ++kk) {
      float a[TM], b[TN];
#pragma unroll
      for (int q = 0; q < TM / 4; ++q) {
        float4 v = *reinterpret_cast<const float4*>(&As[kk][ty * TM + q * 4]);
        a[q * 4 + 0] = v.x; a[q * 4 + 1] = v.y;
        a[q * 4 + 2] = v.z; a[q * 4 + 3] = v.w;
      }
#pragma unroll
      for (int q = 0; q < TN / 4; ++q) {
        float4 v = *reinterpret_cast<const float4*>(&Bs[kk][tx * TN + q * 4]);
        b[q * 4 + 0] = v.x; b[q * 4 + 1] = v.y;
        b[q * 4 + 2] = v.z; b[q * 4 + 3] = v.w;
      }
#pragma unroll
      for (int i = 0; i < TM; ++i)
#pragma unroll
        for (int j = 0; j < TN; ++j)
          acc[i][j] = fmaf(a[i], b[j], acc[i][j]);
    }
  }

  float bb[TN];
#pragma unroll
  for (int q = 0; q < TN / 4; ++q) {
    float4 v = *reinterpret_cast<const float4*>(&bias[col0 + tx * TN + q * 4]);
    bb[q * 4 + 0] = v.x; bb[q * 4 + 1] = v.y;
    bb[q * 4 + 2] = v.z; bb[q * 4 + 3] = v.w;
  }
#pragma unroll
  for (int i = 0; i < TM; ++i) {
    const int r = row0 + ty * TM + i;
#pragma unroll
    for (int q = 0; q < TN / 4; ++q) {
      float4 v;
      float* vp = &v.x;
#pragma unroll
      for (int j = 0; j < 4; ++j) {
        float t = acc[i][q * 4 + j] + bb[q * 4 + j];
        if (RELU) t = fmaxf(t, 0.0f);
        vp[j] = t;
      }
      *reinterpret_cast<float4*>(&C[(size_t)r * N + col0 + tx * TN + q * 4]) = v;
    }
  }
}

// ---------------------------------------------------------------------------
// bf16 MFMA GEMM with TRANSPOSED B (BT[n][k]) -> b128 B-staging.
// DO_LOSS: block(0,0) tid0 finalizes the vq loss scalar.
// ---------------------------------------------------------------------------
template<int WM, bool OUT_BF16, bool DO_LOSS>
__global__ __launch_bounds__(256) void gemm_bf16_mfma(
    const unsigned short* __restrict__ A, const unsigned short* __restrict__ BT,
    const float* __restrict__ bias, void* __restrict__ Cout,
    int M, int N, int K,
    const float* __restrict__ loss_acc, float* __restrict__ loss_out) {
  constexpr int BM = 4 * WM;
  constexpr int MT = WM / 16;

  __shared__ unsigned short As[BM][40];
  __shared__ unsigned short Bs[64][40];

  const int tid  = threadIdx.x;
  const int wave = tid >> 6;
  const int lane = tid & 63;
  const int quad = lane >> 4;
  const int l16  = lane & 15;
  const int row0 = blockIdx.y * BM;
  const int col0 = blockIdx.x * 64;

  if (DO_LOSS && blockIdx.x == 0 && blockIdx.y == 0 && tid == 0)
    loss_out[0] = 0.5f * loss_acc[0] / (float)((size_t)NROWS * GD);

  f32x4 acc[MT][4];
#pragma unroll
  for (int mt = 0; mt < MT; ++mt)
#pragma unroll
    for (int nt = 0; nt < 4; ++nt) acc[mt][nt] = (f32x4){0.f, 0.f, 0.f, 0.f};

  for (int k0 = 0; k0 < K; k0 += 32) {
    __syncthreads();
    if constexpr (BM == 128) {
      const int r = tid >> 1, seg = (tid & 1) * 16;
      const uint4* src = reinterpret_cast<const uint4*>(
          &A[(size_t)(row0 + r) * K + k0 + seg]);
      uint4* dst = reinterpret_cast<uint4*>(&As[r][seg]);
      dst[0] = src[0]; dst[1] = src[1];
    } else {
      const int r = tid >> 2, seg = (tid & 3) * 8;
      *reinterpret_cast<uint4*>(&As[r][seg]) =
          *reinterpret_cast<const uint4*>(&A[(size_t)(row0 + r) * K + k0 + seg]);
    }
    {
      const int n = tid >> 2, kc = (tid & 3) * 8;
      *reinterpret_cast<uint4*>(&Bs[n][kc]) =
          *reinterpret_cast<const uint4*>(&BT[(size_t)(col0 + n) * K + k0 + kc]);
    }
    __syncthreads();

    bf16x8 af[MT], bf[4];
#pragma unroll
    for (int mt = 0; mt < MT; ++mt)
      af[mt] = *reinterpret_cast<const bf16x8*>(
          &As[wave * WM + mt * 16 + l16][quad * 8]);
#pragma unroll
    for (int nt = 0; nt < 4; ++nt)
      bf[nt] = *reinterpret_cast<const bf16x8*>(&Bs[nt * 16 + l16][quad * 8]);
#pragma unroll
    for (int mt = 0; mt < MT; ++mt)
#pragma unroll
      for (int nt = 0; nt < 4; ++nt)
        acc[mt][nt] = __builtin_amdgcn_mfma_f32_16x16x32_bf16(
            af[mt], bf[nt], acc[mt][nt], 0, 0, 0);
  }

#pragma unroll
  for (int mt = 0; mt < MT; ++mt)
#pragma unroll
    for (int nt = 0; nt < 4; ++nt) {
      const int col = col0 + nt * 16 + l16;
      const float bv = bias[col];
#pragma unroll
      for (int r = 0; r < 4; ++r) {
        const int grow = row0 + wave * WM + mt * 16 + quad * 4 + r;
        float v = acc[mt][nt][r] + bv;
        if constexpr (OUT_BF16) {
          v = fmaxf(v, 0.0f);
          ((unsigned short*)Cout)[(size_t)grow * N + col] = f2bf(v);
        } else {
          ((float*)Cout)[(size_t)grow * N + col] = v;
        }
      }
    }
}

// ---------------------------------------------------------------------------
// prep_cn: cn = -0.5*||codebook||^2 (MFMA-accumulator seed for argmax form)
// + zero loss accumulator.  Runs FIRST.
// ---------------------------------------------------------------------------
__global__ void prep_cn(const float* __restrict__ cb, float* __restrict__ cn,
                        float* __restrict__ loss_acc) {
  const int i = blockIdx.x * 256 + threadIdx.x;
  if (i == 0) loss_acc[0] = 0.0f;
  if (i < GQ * KQ) {
    const float* c = cb + (size_t)i * GD;
    float s = 0.0f;
#pragma unroll
    for (int d = 0; d < GD; ++d) s = fmaf(c[d], c[d], s);
    cn[i] = -0.5f * s;
  }
}

// ---------------------------------------------------------------------------
// prep_wT: decoder weights -> TRANSPOSED bf16 (w1bT, w2bT)
// + codebook -> 3-way bf16 split (cbh/cbm/cbl) for the fp32-accurate VQ MFMA.
// MUST run after enc2 (all outputs overlay the then-dead fp32 H region).
// ---------------------------------------------------------------------------
__global__ void prep_wT(const float* __restrict__ w1, const float* __restrict__ w2,
                        const float* __restrict__ cbk,
                        unsigned short* __restrict__ w1bT,
                        unsigned short* __restrict__ w2bT,
                        unsigned short* __restrict__ cbh,
                        unsigned short* __restrict__ cbm,
                        unsigned short* __restrict__ cbl) {
  const int t = blockIdx.x * 256 + threadIdx.x;
  if (t < 16384) {                       // w1: [256 k][512 n] -> w1bT[n][k]
    const int n = t >> 5, k0 = (t & 31) * 8;
    alignas(16) unsigned short o[8];
#pragma unroll
    for (int q = 0; q < 8; ++q) o[q] = f2bf(w1[(size_t)(k0 + q) * HIDDEN + n]);
    *reinterpret_cast<uint4*>(&w1bT[(size_t)n * LATENT + k0]) =
        *reinterpret_cast<const uint4*>(o);
  } else if (t < 20480) {                // w2: [512 k][64 n] -> w2bT[n][k]
    const int u = t - 16384;
    const int n = u >> 6, k0 = (u & 63) * 8;
    alignas(16) unsigned short o[8];
#pragma unroll
    for (int q = 0; q < 8; ++q) o[q] = f2bf(w2[(size_t)(k0 + q) * NBANDS + n]);
    *reinterpret_cast<uint4*>(&w2bT[(size_t)n * HIDDEN + k0]) =
        *reinterpret_cast<const uint4*>(o);
  } else if (t < 53248) {                // codebook 3-way bf16 split, 8 elems/thread
    const int e0 = (t - 20480) * 8;
    alignas(16) unsigned short oh[8], om[8], ol[8];
#pragma unroll
    for (int q = 0; q < 8; ++q) split3(cbk[e0 + q], oh[q], om[q], ol[q]);
    *reinterpret_cast<uint4*>(&cbh[e0]) = *reinterpret_cast<const uint4*>(oh);
    *reinterpret_cast<uint4*>(&cbm[e0]) = *reinterpret_cast<const uint4*>(om);
    *reinterpret_cast<uint4*>(&cbl[e0]) = *reinterpret_cast<const uint4*>(ol);
  }
}

// ---------------------------------------------------------------------------
// vq_mfma v5: VQ search on the MATRIX pipe, LDS-staged via PLAIN loads.
//
// Round-4 diagnosis: latency-bound. ~3750 cy wall per chunk vs ~240 cy of
// MFMA-pipe demand; Occupancy 17% (1.4 waves/SIMD) -> L2 latency exposed;
// every wave redundantly streams the whole split codebook from L2.
// v5: stage each 12.5KB chunk {h,m,l,cn} in LDS, shared by all 4 waves
// (loop L2 traffic /4).  Staging = global->reg->ds_write (NO global_load_lds
// -- round-2's DMA pipeline raced; plain loads + barriers are well-defined).
// Issue-early/write-late: loads for chunk c+2 issue BEFORE compute of c, so
// the ds_write's counted vmcnt and the barrier drain sit under a chunk of
// MFMA.  Double buffer, ONE barrier per chunk.  Fragments consumed in
// nt-PAIRS (ILP=4 across 4 accs, 24 frag VGPRs) to stay <=128 VGPR ->
// 4 waves/SIMD resident (vs round-4's all-nt batch at 120 VGPR but (256,2)).
// Per-accumulator MFMA tier order and select order UNCHANGED -> bit-identical.
//
// LDS reads: each wave's b128 read covers a contiguous 1KB block ->
// conflict-free by construction; cn read is a 16-word broadcast.
// Block: 256 thr = 4 waves x 32 rows = 128 rows; grid (125, 8 groups).
// LDS 2 x 6272 shorts = 25088 B.
// ---------------------------------------------------------------------------
struct VqStg { uint4 h, m, l; float c; };

__device__ __forceinline__ void vq_ldg(
    VqStg& s, const unsigned short* __restrict__ cbh,
    const unsigned short* __restrict__ cbm,
    const unsigned short* __restrict__ cbl,
    const float* __restrict__ cng, int gsh, int ch, int tid) {
  const int o = gsh + ch * 2048 + tid * 8;
  s.h = *reinterpret_cast<const uint4*>(&cbh[o]);
  s.m = *reinterpret_cast<const uint4*>(&cbm[o]);
  s.l = *reinterpret_cast<const uint4*>(&cbl[o]);
  if (tid < 64) s.c = cng[ch * 64 + tid];
}

__device__ __forceinline__ void vq_stl(
    unsigned short (&buf)[6272], const VqStg& s, int tid) {
  *reinterpret_cast<uint4*>(&buf[tid * 8])        = s.h;
  *reinterpret_cast<uint4*>(&buf[2048 + tid * 8]) = s.m;
  *reinterpret_cast<uint4*>(&buf[4096 + tid * 8]) = s.l;
  if (tid < 64) *reinterpret_cast<float*>(&buf[6144 + tid * 2]) = s.c;
}

// One nt-PAIR: 12 MFMAs across 4 accumulators (per-acc tier order:
// ah*h, ah*m, am*h, ah*l, am*m, al*h -- identical to rounds 1/3/4).
__device__ __forceinline__ void vq_pair(
    const bf16x8 (&ah)[2], const bf16x8 (&am)[2], const bf16x8 (&al)[2],
    const unsigned short (&buf)[6272], int laneoff, int nt0, int ch, int l16,
    float (&best)[8], int (&bidx)[8]) {
  bf16x8 Fh[2], Fm[2], Fl[2];
  float  Fc[2];
#pragma unroll
  for (int p = 0; p < 2; ++p) {
    const int off = laneoff + (nt0 + p) * 512;
    Fh[p] = *reinterpret_cast<const bf16x8*>(&buf[off]);
    Fm[p] = *reinterpret_cast<const bf16x8*>(&buf[2048 + off]);
    Fl[p] = *reinterpret_cast<const bf16x8*>(&buf[4096 + off]);
    Fc[p] = *reinterpret_cast<const float*>(&buf[6144 + (((nt0 + p) * 16 + l16) << 1)]);
  }
  f32x4 a00 = {Fc[0], Fc[0], Fc[0], Fc[0]};
  f32x4 a01 = a00;
  f32x4 a10 = {Fc[1], Fc[1], Fc[1], Fc[1]};
  f32x4 a11 = a10;
  a00 = __builtin_amdgcn_mfma_f32_16x16x32_bf16(ah[0], Fh[0], a00, 0, 0, 0);
  a01 = __builtin_amdgcn_mfma_f32_16x16x32_bf16(ah[1], Fh[0], a01, 0, 0, 0);
  a10 = __builtin_amdgcn_mfma_f32_16x16x32_bf16(ah[0], Fh[1], a10, 0, 0, 0);
  a11 = __builtin_amdgcn_mfma_f32_16x16x32_bf16(ah[1], Fh[1], a11, 0, 0, 0);
  a00 = __builtin_amdgcn_mfma_f32_16x16x32_bf16(ah[0], Fm[0], a00, 0, 0, 0);
  a01 = __builtin_amdgcn_mfma_f32_16x16x32_bf16(ah[1], Fm[0], a01, 0, 0, 0);
  a10 = __builtin_amdgcn_mfma_f32_16x16x32_bf16(ah[0], Fm[1], a10, 0, 0, 0);
  a11 = __builtin_amdgcn_mfma_f32_16x16x32_bf16(ah[1], Fm[1], a11, 0, 0, 0);
  a00 = __builtin_amdgcn_mfma_f32_16x16x32_bf16(am[0], Fh[0], a00, 0, 0, 0);
  a01 = __builtin_amdgcn_mfma_f32_16x16x32_bf16(am[1], Fh[0], a01, 0, 0, 0);
  a10 = __builtin_amdgcn_mfma_f32_16x16x32_bf16(am[0], Fh[1], a10, 0, 0, 0);
  a11 = __builtin_amdgcn_mfma_f32_16x16x32_bf16(am[1], Fh[1], a11, 0, 0, 0);
  a00 = __builtin_amdgcn_mfma_f32_16x16x32_bf16(ah[0], Fl[0], a00, 0, 0, 0);
  a01 = __builtin_amdgcn_mfma_f32_16x16x32_bf16(ah[1], Fl[0], a01, 0, 0, 0);
  a10 = __builtin_amdgcn_mfma_f32_16x16x32_bf16(ah[0], Fl[1], a10, 0, 0, 0);
  a11 = __builtin_amdgcn_mfma_f32_16x16x32_bf16(ah[1], Fl[1], a11, 0, 0, 0);
  a00 = __builtin_amdgcn_mfma_f32_16x16x32_bf16(am[0], Fm[0], a00, 0, 0, 0);
  a01 = __builtin_amdgcn_mfma_f32_16x16x32_bf16(am[1], Fm[0], a01, 0, 0, 0);
  a10 = __builtin_amdgcn_mfma_f32_16x16x32_bf16(am[0], Fm[1], a10, 0, 0, 0);
  a11 = __builtin_amdgcn_mfma_f32_16x16x32_bf16(am[1], Fm[1], a11, 0, 0, 0);
  a00 = __builtin_amdgcn_mfma_f32_16x16x32_bf16(al[0], Fh[0], a00, 0, 0, 0);
  a01 = __builtin_amdgcn_mfma_f32_16x16x32_bf16(al[1], Fh[0], a01, 0, 0, 0);
  a10 = __builtin_amdgcn_mfma_f32_16x16x32_bf16(al[0], Fh[1], a10, 0, 0, 0);
  a11 = __builtin_amdgcn_mfma_f32_16x16x32_bf16(al[1], Fh[1], a11, 0, 0, 0);
  // selects in ascending-nt order (same global compare order as before)
  {
    const int code = ch * 64 + nt0 * 16 + l16;
#pragma unroll
    for (int r = 0; r < 4; ++r) {
      if (a00[r] > best[r])     { best[r]     = a00[r]; bidx[r]     = code; }
      if (a01[r] > best[4 + r]) { best[4 + r] = a01[r]; bidx[4 + r] = code; }
    }
  }
  {
    const int code = ch * 64 + (nt0 + 1) * 16 + l16;
#pragma unroll
    for (int r = 0; r < 4; ++r) {
      if (a10[r] > best[r])     { best[r]     = a10[r]; bidx[r]     = code; }
      if (a11[r] > best[4 + r]) { best[4 + r] = a11[r]; bidx[4 + r] = code; }
    }
  }
}

__global__ __launch_bounds__(256, 3) void vq_mfma(
    const float* __restrict__ z_e, const float* __restrict__ cb,
    const float* __restrict__ cnh,           // = -0.5*||c||^2
    const unsigned short* __restrict__ cbh,
    const unsigned short* __restrict__ cbm,
    const unsigned short* __restrict__ cbl,
    float* __restrict__ z_q, unsigned short* __restrict__ zqb,
    float* __restrict__ idx_out, float* __restrict__ loss_acc) {
  __shared__ __align__(16) unsigned short lds[2][6272];

  const int g    = blockIdx.y;
  const int row0 = blockIdx.x * 128;
  const int tid  = threadIdx.x;
  const int wave = tid >> 6;
  const int lane = tid & 63;
  const int quad = lane >> 4;
  const int l16  = lane & 15;

  const int gsh = g * (KQ * GD);           // short offset into cbh/cbm/cbl
  const float* cng = cnh + g * KQ;
  const size_t cb0 = (size_t)g * KQ * GD;
  const int laneoff = l16 * 32 + quad * 8; // shorts within a 4KB tier

  // ---- kick off staging loads for chunk 0 immediately
  VqStg sX, sY;
  vq_ldg(sX, cbh, cbm, cbl, cng, gsh, 0, tid);

  // ---- A fragments: rows wave*32 + mt*16 + l16, dims quad*8..+8 (in-reg split)
  bf16x8 ah[2], am[2], al[2];
#pragma unroll
  for (int mt = 0; mt < 2; ++mt) {
    const float* zp = &z_e[(size_t)(row0 + wave * 32 + mt * 16 + l16) * LATENT
                           + g * GD + quad * 8];
    const float4 x0 = *reinterpret_cast<const float4*>(zp);
    const float4 x1 = *reinterpret_cast<const float4*>(zp + 4);
    const float xv[8] = {x0.x, x0.y, x0.z, x0.w, x1.x, x1.y, x1.z, x1.w};
    bf16x8 vh, vm, vl;
#pragma unroll
    for (int j = 0; j < 8; ++j) {
      unsigned short sh, sm, sl;
      split3(xv[j], sh, sm, sl);
      vh[j] = (short)sh; vm[j] = (short)sm; vl[j] = (short)sl;
    }
    ah[mt] = vh; am[mt] = vm; al[mt] = vl;
  }

  float best[8];
  int   bidx[8];
#pragma unroll
  for (int i = 0; i < 8; ++i) { best[i] = -3.0e38f; bidx[i] = 0; }

  // ---- prologue: chunk 0 into lds[0]; start loads for chunk 1
  vq_stl(lds[0], sX, tid);
  vq_ldg(sY, cbh, cbm, cbl, cng, gsh, 1, tid);
  __syncthreads();

  // ---- main loop: 2 chunks per iteration, ONE barrier per chunk
#pragma unroll 1
  for (int cp = 0; cp < 8; ++cp) {
    const int ch = 2 * cp;
    if (ch < 14) vq_ldg(sX, cbh, cbm, cbl, cng, gsh, ch + 2, tid);
    vq_pair(ah, am, al, lds[0], laneoff, 0, ch, l16, best, bidx);
    vq_pair(ah, am, al, lds[0], laneoff, 2, ch, l16, best, bidx);
    vq_stl(lds[1], sY, tid);           // sY holds chunk ch+1
    __syncthreads();

    const int ch2 = ch + 1;
    if (ch2 < 14) vq_ldg(sY, cbh, cbm, cbl, cng, gsh, ch2 + 2, tid);
    vq_pair(ah, am, al, lds[1], laneoff, 0, ch2, l16, best, bidx);
    vq_pair(ah, am, al, lds[1], laneoff, 2, ch2, l16, best, bidx);
    if (ch2 < 15) {
      vq_stl(lds[0], sX, tid);         // sX holds chunk ch2+1
      __syncthreads();
    }
  }

  // ---- per-row reduce across the 16 l16-lanes (codes == l16 mod 16), then
  // 16 lanes cooperate on the 32-dim epilogue (2 dims each).
  float sse_local = 0.0f;
#pragma unroll
  for (int s8 = 0; s8 < 8; ++s8) {
    float mb = best[s8];
    int   mi = bidx[s8];
#pragma unroll
    for (int m = 1; m < 16; m <<= 1) {
      const float ov = __shfl_xor(mb, m, 64);
      const int   oi = __shfl_xor(mi, m, 64);
      if (ov > mb || (ov == mb && oi < mi)) { mb = ov; mi = oi; }
    }
    // all 16 lanes of this quad-group now agree on (mb, mi)
    const int mt  = s8 >> 2;
    const int r   = s8 & 3;
    const int row = row0 + wave * 32 + mt * 16 + quad * 4 + r;
    const float2 cw = *reinterpret_cast<const float2*>(
        &cb[cb0 + (size_t)mi * GD + 2 * l16]);
    const float2 zv = *reinterpret_cast<const float2*>(
        &z_e[(size_t)row * LATENT + g * GD + 2 * l16]);
    const float d0 = cw.x - zv.x;
    const float d1 = cw.y - zv.y;
    sse_local = fmaf(d0, d0, fmaf(d1, d1, sse_local));
    *reinterpret_cast<float2*>(
        &z_q[(size_t)row * LATENT + g * GD + 2 * l16]) = cw;
    const unsigned pz = (unsigned)f2bf(cw.x) | ((unsigned)f2bf(cw.y) << 16);
    *reinterpret_cast<unsigned*>(
        &zqb[(size_t)row * LATENT + g * GD + 2 * l16]) = pz;
    if (l16 == 0) idx_out[(size_t)row * GQ + g] = (float)mi;
  }

#pragma unroll
  for (int m = 1; m < 64; m <<= 1) sse_local += __shfl_xor(sse_local, m, 64);
  if (lane == 0) atomicAdd(loss_acc, sse_local);
}

// ---------------------------------------------------------------------------
extern "C" void kernel_launch(void* const* d_in, const int* in_sizes, int n_in,
                              void* d_out, int out_size, void* d_ws, size_t ws_size,
                              hipStream_t stream) {
  const float* bands  = (const float*)d_in[0];
  const float* enc_w1 = (const float*)d_in[1];
  const float* enc_b1 = (const float*)d_in[2];
  const float* enc_w2 = (const float*)d_in[3];
  const float* enc_b2 = (const float*)d_in[4];
  const float* cbooks = (const float*)d_in[5];
  const float* dec_w1 = (const float*)d_in[6];
  const float* dec_b1 = (const float*)d_in[7];
  const float* dec_w2 = (const float*)d_in[8];
  const float* dec_b2 = (const float*)d_in[9];

  float* out = (float*)d_out;
  float* ws  = (float*)d_ws;

  float* bands_hat = out + OUT_BH;
  float* z_e       = out + OUT_ZE;
  float* z_q       = out + OUT_ZQ;
  float* idx_f     = out + OUT_IDX;
  float* loss_out  = out + OUT_LOSS;

  float* H        = ws + WS_H;
  float* cn       = ws + WS_CN;
  float* loss_acc = ws + WS_LOSS;
  unsigned short* h2bf = (unsigned short*)(ws + WS_H2BF_F);
  unsigned short* zqb  = (unsigned short*)(ws + WS_ZQB_F);
  unsigned short* w1bT = (unsigned short*)(ws + WS_W1B_F);
  unsigned short* w2bT = (unsigned short*)(ws + WS_W2B_F);
  unsigned short* cbh  = (unsigned short*)(ws + WS_CBH_F);
  unsigned short* cbm  = (unsigned short*)(ws + WS_CBM_F);
  unsigned short* cbl  = (unsigned short*)(ws + WS_CBL_F);

  // cn (= -0.5||c||^2) + loss zero (safe: outside H region)
  prep_cn<<<dim3(32), dim3(256), 0, stream>>>(cbooks, cn, loss_acc);

  // Encoder (fp32): H = relu(bands@W1+b1); z_e = H@W2+b2 (enc2 BK=32)
  gemm_f32<128, 8, 8, 16, true ><<<dim3(HIDDEN / 128, NROWS / 128), dim3(256), 0, stream>>>(
      bands, enc_w1, enc_b1, H, NROWS, HIDDEN, NBANDS);
  gemm_f32<64, 4, 8, 32, false><<<dim3(LATENT / 64, NROWS / 128), dim3(256), 0, stream>>>(
      H, enc_w2, enc_b2, z_e, NROWS, LATENT, HIDDEN);

  // Decoder weights -> transposed bf16; codebook -> 3-way bf16 split
  // (H is dead now; overlays are safe)
  prep_wT<<<dim3(208), dim3(256), 0, stream>>>(
      dec_w1, dec_w2, cbooks, w1bT, w2bT, cbh, cbm, cbl);

  // VQ on the matrix pipe (fp32-class accuracy via 6-MFMA split), LDS-staged
  vq_mfma<<<dim3(NROWS / 128, GQ), dim3(256), 0, stream>>>(
      z_e, cbooks, cn, cbh, cbm, cbl, z_q, zqb, idx_f, loss_acc);

  // Decoder (bf16 MFMA, transposed-weight staging); dec1 finalizes loss
  gemm_bf16_mfma<32, true, true ><<<dim3(HIDDEN / 64, NROWS / 128), dim3(256), 0, stream>>>(
      zqb, w1bT, dec_b1, (void*)h2bf, NROWS, HIDDEN, LATENT, loss_acc, loss_out);
  gemm_bf16_mfma<16, false, false><<<dim3(NBANDS / 64, NROWS / 64), dim3(256), 0, stream>>>(
      h2bf, w2bT, dec_b2, (void*)bands_hat, NROWS, NBANDS, HIDDEN, loss_acc, loss_out);
}